// Round 1
// baseline (94.125 us; speedup 1.0000x reference)
//
#include <hip/hip_runtime.h>
#include <stdint.h>

// Problem constants: z (32,64,32,32) fp32, codebook (1024,64) fp32
#define NUM_E     1024
#define DIM       64
#define NPOS      32768      // 32*32*32 spatial positions
#define OUT_ELEMS 2097152    // 32*64*32*32

typedef short  short8  __attribute__((ext_vector_type(8)));   // 8 bf16 = 4 VGPRs
typedef float  f32x4   __attribute__((ext_vector_type(4)));

__device__ __forceinline__ unsigned int bf16r(float f) {
    uint32_t u = __builtin_bit_cast(uint32_t, f);
    return (u + 0x8000u) >> 16;            // round-half-up
}
__device__ __forceinline__ unsigned int pack2(float a, float b) {
    return bf16r(a) | (bf16r(b) << 16);
}

// ---------------- prep: bf16 codebook + biased norm (1 - 0.5*||c||^2) ----------------
// 64 blocks x 256 threads; 16 lanes per codebook row; float4 coalesced loads.
__global__ __launch_bounds__(256) void vq_prep(const float* __restrict__ cb,
                                               unsigned short* __restrict__ cbb,
                                               float* __restrict__ g0b,
                                               float* __restrict__ loss_out) {
    const int tid  = threadIdx.x;
    const int lane = tid & 63;
    const int w    = tid >> 6;
    const int quad = lane >> 4, r16 = lane & 15;
    const int row  = blockIdx.x * 16 + w * 4 + quad;
    if (blockIdx.x == 0 && tid == 0) loss_out[0] = 0.0f;   // d_out poisoned pre-launch

    const float4 v = *reinterpret_cast<const float4*>(cb + row * 64 + r16 * 4);
    float s = v.x * v.x + v.y * v.y + v.z * v.z + v.w * v.w;
#pragma unroll
    for (int d = 1; d < 16; d <<= 1) s += __shfl_xor(s, d, 64);  // sum within 16-lane row group
    if (r16 == 0) g0b[row] = 1.0f - 0.5f * s;   // +1 bias keeps scores positive (uint-key trick)

    uint2 p;
    p.x = pack2(v.x, v.y);
    p.y = pack2(v.z, v.w);
    *reinterpret_cast<uint2*>(cbb + row * 64 + r16 * 4) = p;
}

// ---------------- main: 32-position tiles, 4 blocks/CU, MFMA distances + argmax-key ----------------
// Block: 256 threads (4 waves) = 32 consecutive positions. Wave w scans entries [256w, 256w+256).
// Score g = z.c - 0.5||c||^2 + 1 (max <=> min dist; +1 => positive => uint cmp == float cmp).
// Key = (g_bits & ~0x3FF) | (1023-idx). Pairwise combine -> v_max3_u32 (1.5 VALU/score).
#define ZP 68   // LDS row stride (floats): 64 + 4 pad — 16B-aligned rows for ds_read_b128
__global__ __launch_bounds__(256, 4) void vq_main(
    const float* __restrict__ z,
    const float* __restrict__ cb,            // fp32 codebook (exact gather)
    const unsigned short* __restrict__ cbb,  // bf16 codebook
    const float* __restrict__ g0b,           // 1 - 0.5*||c_k||^2
    float* __restrict__ out,
    float* __restrict__ loss_out)
{
    const int tid  = threadIdx.x;
    const int lane = tid & 63;
    const int w    = __builtin_amdgcn_readfirstlane(tid >> 6);  // 0..3, wave-uniform
    const int quad = lane >> 4;
    const int r16  = lane & 15;

    const int n0    = blockIdx.x * 32;           // first position of this block
    const int zbase = ((n0 >> 10) << 16) + (n0 & 1023);   // float index of (b, c=0, hw0)

    __shared__ float zt[32][ZP];                 // [position][channel], exact fp32 (~8.5 KB)
    __shared__ unsigned int cand[4][32];
    __shared__ float lsum[4];

    // ---- stage block's 8KB z-tile: 2 coalesced float4 loads/thread, transposed LDS writes.
    // Write bank = (16*(l&1) + (l>>3) + const) mod 32 -> 16 distinct banks, 4-way (near-free;
    // the 64-pos version had cc spanning only 4 values -> 2 banks -> 32-way).
#pragma unroll
    for (int l = 0; l < 2; ++l) {
        const int id = tid + (l << 8);           // 0..511
        const int cc = id >> 3;                  // channel 0..63
        const int f4 = id & 7;                   // position quad 0..7
        const float4 v = *reinterpret_cast<const float4*>(z + zbase + cc * 1024 + f4 * 4);
        zt[f4 * 4 + 0][cc] = v.x;
        zt[f4 * 4 + 1][cc] = v.y;
        zt[f4 * 4 + 2][cc] = v.z;
        zt[f4 * 4 + 3][cc] = v.w;
    }
    __syncthreads();

    // ---- A fragments from LDS: A[m=r16][k=quad*8+j], m-position = pt*16+r16 (conflict-free b128)
    short8 afrag[2][2];
#pragma unroll
    for (int pt = 0; pt < 2; ++pt) {
#pragma unroll
        for (int half = 0; half < 2; ++half) {
            const float* src = &zt[pt * 16 + r16][quad * 8 + half * 32];
            const float4 a0 = *reinterpret_cast<const float4*>(src);
            const float4 a1 = *reinterpret_cast<const float4*>(src + 4);
            union { short8 s; uint32_t u[4]; } fr;
            fr.u[0] = pack2(a0.x, a0.y);
            fr.u[1] = pack2(a0.z, a0.w);
            fr.u[2] = pack2(a1.x, a1.y);
            fr.u[3] = pack2(a1.z, a1.w);
            afrag[pt][half] = fr.s;
        }
    }

    // ---- scan this wave's 256-entry quarter in 16-entry tiles, paired for max3
    const int e0 = (w << 8) + r16;
    unsigned int best[2][4];
#pragma unroll
    for (int pt = 0; pt < 2; ++pt)
#pragma unroll
        for (int r = 0; r < 4; ++r) best[pt][r] = 0u;

    auto subtile = [&](int itx, unsigned int (&kk)[2][4]) {
        const int ecol = e0 + itx * 16;                 // this lane's column entry
        const float nh = g0b[ecol];                     // biased: 1 - 0.5||c||^2
        const unsigned int idxenc = (unsigned int)(1023 - ecol);
        const short8 bf0 = *reinterpret_cast<const short8*>(cbb + ecol * 64 + quad * 8);
        const short8 bf1 = *reinterpret_cast<const short8*>(cbb + ecol * 64 + quad * 8 + 32);
        f32x4 cvec = {nh, nh, nh, nh};
#pragma unroll
        for (int pt = 0; pt < 2; ++pt) {
            f32x4 acc = __builtin_amdgcn_mfma_f32_16x16x32_bf16(afrag[pt][0], bf0, cvec, 0, 0, 0);
            acc = __builtin_amdgcn_mfma_f32_16x16x32_bf16(afrag[pt][1], bf1, acc, 0, 0, 0);
            // C/D layout: col = lane&15 (entry), row = quad*4 + r (position)
#pragma unroll
            for (int r = 0; r < 4; ++r)
                kk[pt][r] = (__builtin_bit_cast(unsigned int, acc[r]) & 0xFFFFFC00u) | idxenc;
        }
    };

#pragma unroll
    for (int it = 0; it < 16; it += 2) {
        unsigned int ka[2][4], kb[2][4];
        subtile(it,     ka);
        subtile(it + 1, kb);
#pragma unroll
        for (int pt = 0; pt < 2; ++pt)
#pragma unroll
            for (int r = 0; r < 4; ++r) {
                const unsigned int m = ka[pt][r] > kb[pt][r] ? ka[pt][r] : kb[pt][r];
                best[pt][r] = best[pt][r] > m ? best[pt][r] : m;   // -> v_max3_u32
            }
    }

    // ---- cross-lane max within each 16-lane group (keys carry the index)
#pragma unroll
    for (int pt = 0; pt < 2; ++pt) {
#pragma unroll
        for (int r = 0; r < 4; ++r) {
            unsigned int key = best[pt][r];
#pragma unroll
            for (int d = 1; d < 16; d <<= 1) {
                const unsigned int o = __shfl_xor(key, d, 64);
                key = (o > key) ? o : key;
            }
            if (r16 == 0) cand[w][pt * 16 + quad * 4 + r] = key;   // index = position in tile
        }
    }
    __syncthreads();

    // ---- combine 4 wave-quarters; thread (pos = tid&31, cg = tid>>5) handles 8 channels
    const int pos = tid & 31;
    const int cg  = tid >> 5;                    // 0..7 -> channels [8cg, 8cg+8)
    const unsigned int k0 = cand[0][pos], k1 = cand[1][pos];
    const unsigned int k2 = cand[2][pos], k3 = cand[3][pos];
    unsigned int fk        = k0 > k1 ? k0 : k1;
    const unsigned int fk2 = k2 > k3 ? k2 : k3;
    fk = fk > fk2 ? fk : fk2;
    const int widx = 1023 - (int)(fk & 1023u);

    // ---- gather exact fp32 codebook row; z from LDS (exact); coalesced out; fused loss
    float ls = 0.0f;
    const int c0 = cg * 8;
    const float4 cva = *reinterpret_cast<const float4*>(cb + widx * 64 + c0);
    const float4 cvb = *reinterpret_cast<const float4*>(cb + widx * 64 + c0 + 4);
    const float4 zla = *reinterpret_cast<const float4*>(&zt[pos][c0]);
    const float4 zlb = *reinterpret_cast<const float4*>(&zt[pos][c0 + 4]);
    const float q[8]  = {cva.x, cva.y, cva.z, cva.w, cvb.x, cvb.y, cvb.z, cvb.w};
    const float zz[8] = {zla.x, zla.y, zla.z, zla.w, zlb.x, zlb.y, zlb.z, zlb.w};
#pragma unroll
    for (int j = 0; j < 8; ++j) {
        out[zbase + (c0 + j) * 1024 + pos] = q[j];   // lanes <-> consecutive positions
        const float d = q[j] - zz[j];
        ls += d * d;
    }
    // wave reduce, then one atomic per block
#pragma unroll
    for (int d = 1; d < 64; d <<= 1) ls += __shfl_xor(ls, d, 64);
    if (lane == 0) lsum[w] = ls;
    __syncthreads();
    if (tid == 0) {
        const float t = (lsum[0] + lsum[1] + lsum[2] + lsum[3]) * (1.25f / (float)OUT_ELEMS);
        atomicAdd(loss_out, t);
    }
}

extern "C" void kernel_launch(void* const* d_in, const int* in_sizes, int n_in,
                              void* d_out, int out_size, void* d_ws, size_t ws_size,
                              hipStream_t stream) {
    const float* z  = (const float*)d_in[0];   // (32,64,32,32) fp32
    const float* cb = (const float*)d_in[1];   // (1024,64) fp32
    unsigned short* cbb = (unsigned short*)d_ws;                       // 128 KB bf16 codebook
    float* g0b  = (float*)((char*)d_ws + NUM_E * DIM * sizeof(unsigned short)); // 4 KB biased norms
    float* out  = (float*)d_out;               // zq (2097152) then loss (1)
    float* loss = out + OUT_ELEMS;

    vq_prep<<<NUM_E / 16, 256, 0, stream>>>(cb, cbb, g0b, loss);
    vq_main<<<NPOS / 32, 256, 0, stream>>>(z, cb, cbb, g0b, out, loss);
}

// Round 2
// 81.717 us; speedup vs baseline: 1.1518x; 1.1518x over previous
//
#include <hip/hip_runtime.h>
#include <stdint.h>

// Problem constants: z (32,64,32,32) fp32, codebook (1024,64) fp32
#define NUM_E     1024
#define DIM       64
#define NPOS      32768      // 32*32*32 spatial positions
#define OUT_ELEMS 2097152    // 32*64*32*32

typedef short  short8  __attribute__((ext_vector_type(8)));   // 8 bf16 = 4 VGPRs
typedef float  f32x4   __attribute__((ext_vector_type(4)));

__device__ __forceinline__ unsigned int bf16r(float f) {
    uint32_t u = __builtin_bit_cast(uint32_t, f);
    return (u + 0x8000u) >> 16;            // round-half-up
}
__device__ __forceinline__ unsigned int pack2(float a, float b) {
    return bf16r(a) | (bf16r(b) << 16);
}

// ---------------- prep: bf16 codebook + biased norm (1 - 0.5*||c||^2) ----------------
// 64 blocks x 256 threads; 16 lanes per codebook row; float4 coalesced loads.
__global__ __launch_bounds__(256) void vq_prep(const float* __restrict__ cb,
                                               unsigned short* __restrict__ cbb,
                                               float* __restrict__ g0b,
                                               float* __restrict__ loss_out) {
    const int tid  = threadIdx.x;
    const int lane = tid & 63;
    const int w    = tid >> 6;
    const int quad = lane >> 4, r16 = lane & 15;
    const int row  = blockIdx.x * 16 + w * 4 + quad;
    if (blockIdx.x == 0 && tid == 0) loss_out[0] = 0.0f;   // d_out poisoned pre-launch

    const float4 v = *reinterpret_cast<const float4*>(cb + row * 64 + r16 * 4);
    float s = v.x * v.x + v.y * v.y + v.z * v.z + v.w * v.w;
#pragma unroll
    for (int d = 1; d < 16; d <<= 1) s += __shfl_xor(s, d, 64);  // sum within 16-lane row group
    if (r16 == 0) g0b[row] = 1.0f - 0.5f * s;   // +1 bias keeps scores positive (uint-key trick)

    uint2 p;
    p.x = pack2(v.x, v.y);
    p.y = pack2(v.z, v.w);
    *reinterpret_cast<uint2*>(cbb + row * 64 + r16 * 4) = p;
}

// ---------------- main: LDS-staged z + MFMA distances + argmax-key + gather + loss ----------------
// Round-0 geometry (64 positions/block, 4 waves, 2 blocks/CU) + depth-3 register prefetch
// in the codebook scan: the L2 loads for iteration it+3 are issued while iteration it
// computes, hiding ~200-300 cyc L2 latency that the non-pipelined loop exposed serially.
// Score g = z.c - 0.5||c||^2 + 1 (max <=> min dist; +1 => positive => uint cmp == float cmp).
// Key = (g_bits & ~0x3FF) | (1023-idx): one v_and_or_b32 + one v_max_u32 per element.
#define ZP 68   // LDS row stride (floats): 64 + 4 pad — 16B-aligned, breaks pow-2 bank aliasing
__global__ __launch_bounds__(256, 2) void vq_main(
    const float* __restrict__ z,
    const float* __restrict__ cb,            // fp32 codebook (exact gather)
    const unsigned short* __restrict__ cbb,  // bf16 codebook
    const float* __restrict__ g0b,           // 1 - 0.5*||c_k||^2
    float* __restrict__ out,
    float* __restrict__ loss_out)
{
    const int tid  = threadIdx.x;
    const int lane = tid & 63;
    const int w    = __builtin_amdgcn_readfirstlane(tid >> 6);  // 0..3, wave-uniform
    const int quad = lane >> 4;
    const int r16  = lane & 15;

    const int n0    = blockIdx.x * 64;           // first position of this block
    const int b     = n0 >> 10;                  // batch (64 | 1024: tiles never cross batches)
    const int zbase = b * 65536 + (n0 & 1023);   // float index of (b, c=0, hw0)

    __shared__ float zt[64][ZP];                 // [position][channel], exact fp32
    __shared__ unsigned int cand[4][64];
    __shared__ float lsum[4];

    // ---- stage block's 16KB z-tile: coalesced float4 global loads, transposed LDS writes
#pragma unroll
    for (int p = 0; p < 4; ++p) {
        const int cc = p * 16 + (tid >> 4);      // channel 0..63
        const int f4 = tid & 15;                 // position quad 0..15
        const float4 v = *reinterpret_cast<const float4*>(z + zbase + cc * 1024 + f4 * 4);
        zt[f4 * 4 + 0][cc] = v.x;
        zt[f4 * 4 + 1][cc] = v.y;
        zt[f4 * 4 + 2][cc] = v.z;
        zt[f4 * 4 + 3][cc] = v.w;
    }
    __syncthreads();

    // ---- A fragments from LDS: A[m=r16][k=quad*8+j], m-position = pt*16+r16
    short8 afrag[4][2];
#pragma unroll
    for (int pt = 0; pt < 4; ++pt) {
#pragma unroll
        for (int half = 0; half < 2; ++half) {
            const float* src = &zt[pt * 16 + r16][quad * 8 + half * 32];
            const float4 a0 = *reinterpret_cast<const float4*>(src);
            const float4 a1 = *reinterpret_cast<const float4*>(src + 4);
            union { short8 s; uint32_t u[4]; } fr;
            fr.u[0] = pack2(a0.x, a0.y);
            fr.u[1] = pack2(a0.z, a0.w);
            fr.u[2] = pack2(a1.x, a1.y);
            fr.u[3] = pack2(a1.z, a1.w);
            afrag[pt][half] = fr.s;
        }
    }

    // ---- scan this wave's 256-entry quarter in 16-entry tiles, depth-3 prefetch pipeline
    const int e0 = w * 256 + r16;
    unsigned int best[4][4];
#pragma unroll
    for (int pt = 0; pt < 4; ++pt)
#pragma unroll
        for (int r = 0; r < 4; ++r) best[pt][r] = 0u;

    // rotating prefetch buffers (named, fully unrolled -> all register, no scratch)
    short8 pbf0_a, pbf1_a, pbf0_b, pbf1_b, pbf0_c, pbf1_c;
    float  pnh_a, pnh_b, pnh_c;

#define ISSUE(itx, B0, B1, NH)                                                    \
    {                                                                             \
        const int ecol_ = e0 + (itx) * 16;                                        \
        NH = g0b[ecol_];                                                          \
        B0 = *reinterpret_cast<const short8*>(cbb + ecol_ * 64 + quad * 8);       \
        B1 = *reinterpret_cast<const short8*>(cbb + ecol_ * 64 + quad * 8 + 32);  \
    }

#define CONSUME(itx, B0, B1, NH)                                                  \
    {                                                                             \
        const unsigned int idxenc_ = (unsigned int)(1023 - (e0 + (itx) * 16));    \
        const f32x4 cvec_ = {NH, NH, NH, NH};                                     \
        _Pragma("unroll")                                                         \
        for (int pt = 0; pt < 4; ++pt) {                                          \
            f32x4 acc = __builtin_amdgcn_mfma_f32_16x16x32_bf16(                  \
                afrag[pt][0], B0, cvec_, 0, 0, 0);                                \
            acc = __builtin_amdgcn_mfma_f32_16x16x32_bf16(                        \
                afrag[pt][1], B1, acc, 0, 0, 0);                                  \
            _Pragma("unroll")                                                     \
            for (int r = 0; r < 4; ++r) {                                         \
                unsigned int k_ = (__builtin_bit_cast(unsigned int, acc[r])       \
                                   & 0xFFFFFC00u) | idxenc_;                      \
                best[pt][r] = best[pt][r] > k_ ? best[pt][r] : k_;                \
            }                                                                     \
        }                                                                         \
    }

    ISSUE(0, pbf0_a, pbf1_a, pnh_a);
    ISSUE(1, pbf0_b, pbf1_b, pnh_b);
    ISSUE(2, pbf0_c, pbf1_c, pnh_c);
#pragma unroll
    for (int it = 0; it < 16; it += 3) {
        CONSUME(it, pbf0_a, pbf1_a, pnh_a);
        if (it + 3 < 16) ISSUE(it + 3, pbf0_a, pbf1_a, pnh_a);
        if (it + 1 < 16) {
            CONSUME(it + 1, pbf0_b, pbf1_b, pnh_b);
            if (it + 4 < 16) ISSUE(it + 4, pbf0_b, pbf1_b, pnh_b);
        }
        if (it + 2 < 16) {
            CONSUME(it + 2, pbf0_c, pbf1_c, pnh_c);
            if (it + 5 < 16) ISSUE(it + 5, pbf0_c, pbf1_c, pnh_c);
        }
    }
#undef ISSUE
#undef CONSUME

    // ---- cross-lane max within each 16-lane group (keys carry the index)
#pragma unroll
    for (int pt = 0; pt < 4; ++pt) {
#pragma unroll
        for (int r = 0; r < 4; ++r) {
            unsigned int key = best[pt][r];
#pragma unroll
            for (int d = 1; d < 16; d <<= 1) {
                unsigned int o = __shfl_xor(key, d, 64);
                key = (o > key) ? o : key;
            }
            if (r16 == 0) cand[w][pt * 16 + quad * 4 + r] = key;   // index = position in tile
        }
    }
    __syncthreads();

    // ---- combine the 4 wave-quarters; lane picks position n0+lane's winner
    unsigned int k0 = cand[0][lane], k1 = cand[1][lane];
    unsigned int k2 = cand[2][lane], k3 = cand[3][lane];
    unsigned int fk  = k0 > k1 ? k0 : k1;
    unsigned int fk2 = k2 > k3 ? k2 : k3;
    fk = fk > fk2 ? fk : fk2;
    const int widx = 1023 - (int)(fk & 1023u);

    // ---- gather exact fp32 codebook row; z from LDS (exact); coalesced out; fused loss
    float ls = 0.0f;
#pragma unroll
    for (int i4 = 0; i4 < 4; ++i4) {
        const int c = w * 16 + i4 * 4;
        const float4 cv = *reinterpret_cast<const float4*>(cb + widx * 64 + c);
        const float4 zl = *reinterpret_cast<const float4*>(&zt[lane][c]);
        const float q4[4] = {cv.x, cv.y, cv.z, cv.w};
        const float z4[4] = {zl.x, zl.y, zl.z, zl.w};
#pragma unroll
        for (int j = 0; j < 4; ++j) {
            out[zbase + (c + j) * 1024 + lane] = q4[j];   // lane <-> position n0+lane
            const float d = q4[j] - z4[j];
            ls += d * d;
        }
    }
    // wave reduce, then one atomic per block
#pragma unroll
    for (int d = 1; d < 64; d <<= 1) ls += __shfl_xor(ls, d, 64);
    if (lane == 0) lsum[w] = ls;
    __syncthreads();
    if (tid == 0) {
        const float t = (lsum[0] + lsum[1] + lsum[2] + lsum[3]) * (1.25f / (float)OUT_ELEMS);
        atomicAdd(loss_out, t);
    }
}

extern "C" void kernel_launch(void* const* d_in, const int* in_sizes, int n_in,
                              void* d_out, int out_size, void* d_ws, size_t ws_size,
                              hipStream_t stream) {
    const float* z  = (const float*)d_in[0];   // (32,64,32,32) fp32
    const float* cb = (const float*)d_in[1];   // (1024,64) fp32
    unsigned short* cbb = (unsigned short*)d_ws;                       // 128 KB bf16 codebook
    float* g0b  = (float*)((char*)d_ws + NUM_E * DIM * sizeof(unsigned short)); // 4 KB biased norms
    float* out  = (float*)d_out;               // zq (2097152) then loss (1)
    float* loss = out + OUT_ELEMS;

    vq_prep<<<NUM_E / 16, 256, 0, stream>>>(cb, cbb, g0b, loss);
    vq_main<<<NPOS / 64, 256, 0, stream>>>(z, cb, cbb, g0b, out, loss);
}